// Round 12
// baseline (245.126 us; speedup 1.0000x reference)
//
#include <hip/hip_runtime.h>

#define NROW 8192
#define INF  512
#define OUTF 256
#define M_ELEM (NROW * OUTF)   // 2,097,152 f32 per output matrix
#define NSTEP 16               // K-steps of 512

typedef __bf16 v8bf __attribute__((ext_vector_type(8)));
typedef __bf16 v4bf __attribute__((ext_vector_type(4)));
typedef float  v4f  __attribute__((ext_vector_type(4)));

__device__ __forceinline__ v8bf cvt_bf8(v4f u0, v4f u1) {
  v8bf v;
  v[0]=(__bf16)u0[0]; v[1]=(__bf16)u0[1]; v[2]=(__bf16)u0[2]; v[3]=(__bf16)u0[3];
  v[4]=(__bf16)u1[0]; v[5]=(__bf16)u1[1]; v[6]=(__bf16)u1[2]; v[7]=(__bf16)u1[3];
  return v;
}

// ---------------------------------------------------------------------------
// Kernel A: seq = feat @ W^T, bf16 MFMA, output in B-fragment-packed layout:
//   elem(m,o) -> (((m>>5)*16 + (o>>4))*64 + ((m>>3)&3)*16 + (o&15))*8 + (m&7)
// ---------------------------------------------------------------------------
__global__ __launch_bounds__(256) void seq_fts_kernel(
    const float* __restrict__ feat, const float* __restrict__ W,
    __bf16* __restrict__ Bp) {
  const int tid  = threadIdx.x;
  const int lane = tid & 63, w = tid >> 6;
  const int llo  = lane & 15, lhi = lane >> 4;
  const int row0 = blockIdx.x * 64;
  const int col0 = w * 64;

  v4f acc[4][4] = {};
#pragma unroll 1
  for (int kb = 0; kb < INF / 32; ++kb) {
    const int kofs = kb * 32 + lhi * 8;
    v8bf a[4], b[4];
#pragma unroll
    for (int i = 0; i < 4; ++i) {
      const float* p = feat + (size_t)(row0 + i * 16 + llo) * INF + kofs;
      a[i] = cvt_bf8(*(const v4f*)p, *(const v4f*)(p + 4));
    }
#pragma unroll
    for (int i = 0; i < 4; ++i) {
      const float* p = W + (size_t)(col0 + i * 16 + llo) * INF + kofs;
      b[i] = cvt_bf8(*(const v4f*)p, *(const v4f*)(p + 4));
    }
#pragma unroll
    for (int ri = 0; ri < 4; ++ri)
#pragma unroll
      for (int ci = 0; ci < 4; ++ci)
        acc[ri][ci] = __builtin_amdgcn_mfma_f32_16x16x32_bf16(
            a[ri], b[ci], acc[ri][ci], 0, 0, 0);
  }
#pragma unroll
  for (int ri = 0; ri < 4; ++ri)
#pragma unroll
    for (int ci = 0; ci < 4; ++ci) {
      const int mf = row0 + ri * 16 + lhi * 4;
      const int o  = col0 + ci * 16 + llo;
      size_t e = (((size_t)(mf >> 5) * 16 + (o >> 4)) * 64 +
                  ((mf >> 3) & 3) * 16 + (o & 15)) * 8 + (mf & 7);
      v4bf v;
      v[0] = (__bf16)acc[ri][ci][0]; v[1] = (__bf16)acc[ri][ci][1];
      v[2] = (__bf16)acc[ri][ci][2]; v[3] = (__bf16)acc[ri][ci][3];
      *(v4bf*)(Bp + e) = v;
    }
}

// ---------------------------------------------------------------------------
// Kernel B: out = prelu(adj @ seq + bias).
// DOSE-RESPONSE on burst contiguity: BK=512 -> each adj row staged as a
// 2 KB CONTIGUOUS extent (2 back-to-back 1KB global_load_lds, NT). BM=32,
// 4 waves, D=2 LDS (128 KB, 1 block/CU). XOR-swizzle via pre-swizzled
// source slot (key<32 -> bijective within the 2 KB row, flips only low
// 5 slot bits). B-first FIFO per step as R9/R11.
// ---------------------------------------------------------------------------
__global__ __launch_bounds__(256) void gcn_agg_kernel(
    const float* __restrict__ adjA, const float* __restrict__ adjB,
    const __bf16* __restrict__ Bp, const float* __restrict__ bias,
    const float* __restrict__ prelu_a, float* __restrict__ out) {
  const int tid  = threadIdx.x;
  const int lane = tid & 63, w = tid >> 6;      // 4 waves
  const int llo  = lane & 15, lhi = lane >> 4;
  const int row0 = blockIdx.x * 32;
  const int z    = blockIdx.y;
  const float* __restrict__ adj = z ? adjB : adjA;

  __shared__ __align__(16) char LdsA[2][65536];   // 2 x (32 rows x 2 KB)

  v4f acc[2][4] = {};   // [rt 0..1][ci 0..3]; wave w owns cols [w*64,(w+1)*64)

  // --- A staging: 8 rows/wave, each = one 2 KB contiguous extent (2 instr).
  // LDS row r slot s (16B units, s=0..127) holds source slot s ^ key(r).
  auto stage_a = [&](int buf, int t) {
#pragma unroll
    for (int i = 0; i < 8; ++i) {
      const int r   = w * 8 + i;
      const int key = ((r & 15) << 1) | ((r >> 3) & 1);   // < 32
      const float* rowp = adj + (size_t)(row0 + r) * NROW + t * 512;
#pragma unroll
      for (int h = 0; h < 2; ++h) {
        const float* src = rowp + ((h * 64 + (lane ^ key)) << 2);
        __builtin_amdgcn_global_load_lds(
            (const __attribute__((address_space(1))) void*)src,
            (__attribute__((address_space(3))) void*)(
                &LdsA[buf][r * 2048 + h * 1024]),
            16, 0, 2 /* NT */);
      }
    }
  };

  // --- B fragments, quarter-step granularity: [4 kg][4 ci] = 64 VGPR.
  const __bf16* __restrict__ Bpw = Bp + ((size_t)(w * 4) * 64 + lane) * 8;
  auto load_bq = [&](int t, int q, v8bf (&b)[4][4]) {
#pragma unroll
    for (int kk = 0; kk < 4; ++kk)
#pragma unroll
      for (int ci = 0; ci < 4; ++ci)
        b[kk][ci] = *(const v8bf*)(
            Bpw + ((size_t)((t * 16 + q * 4 + kk) * 16 + ci)) * 512);
  };

  auto compute_q = [&](int buf, int q, v8bf (&b)[4][4]) {
    const char* ab = &LdsA[buf][0];
#pragma unroll
    for (int kk = 0; kk < 4; ++kk) {
      const int kg = q * 4 + kk;
      v8bf af[2];
#pragma unroll
      for (int rt = 0; rt < 2; ++rt) {
        const int r   = rt * 16 + llo;
        const int key = ((r & 15) << 1) | ((r >> 3) & 1);
        const char* base = ab + r * 2048;
        v4f u0 = *(const v4f*)(base + (((kg * 8 + lhi * 2    ) ^ key) << 4));
        v4f u1 = *(const v4f*)(base + (((kg * 8 + lhi * 2 + 1) ^ key) << 4));
        af[rt] = cvt_bf8(u0, u1);
      }
#pragma unroll
      for (int ci = 0; ci < 4; ++ci)
#pragma unroll
        for (int rt = 0; rt < 2; ++rt)
          acc[rt][ci] = __builtin_amdgcn_mfma_f32_16x16x32_bf16(
              af[rt], b[kk][ci], acc[rt][ci], 0, 0, 0);
    }
  };

  stage_a(0, 0);

  v8bf b0[4][4], b1[4][4];
#pragma unroll 1
  for (int t = 0; t < NSTEP; ++t) {
    // Only A(t)'s 16 loads outstanding here (B retired by compute waits).
    asm volatile("s_waitcnt vmcnt(0)" ::: "memory");
    __builtin_amdgcn_s_barrier();
    load_bq(t, 0, b0);                                // oldest in FIFO
    __builtin_amdgcn_sched_barrier(0);
    load_bq(t, 1, b1);
    __builtin_amdgcn_sched_barrier(0);
    if (t + 1 < NSTEP) stage_a((t + 1) & 1, t + 1);   // newest in FIFO
    __builtin_amdgcn_sched_barrier(0);
    compute_q(t & 1, 0, b0);
    load_bq(t, 2, b0);
    compute_q(t & 1, 1, b1);
    load_bq(t, 3, b1);
    compute_q(t & 1, 2, b0);
    compute_q(t & 1, 3, b1);
  }

  // epilogue: bias + prelu, direct store
  const float slope = prelu_a[0];
  float* __restrict__ outp = out + (size_t)z * M_ELEM;
#pragma unroll
  for (int ci = 0; ci < 4; ++ci) {
    const int o  = w * 64 + ci * 16 + llo;
    const float bs = bias[o];
#pragma unroll
    for (int rt = 0; rt < 2; ++rt) {
      const int m = row0 + rt * 16 + lhi * 4;
#pragma unroll
      for (int r = 0; r < 4; ++r) {
        float v = acc[rt][ci][r] + bs;
        outp[(size_t)(m + r) * OUTF + o] = v >= 0.f ? v : slope * v;
      }
    }
  }
}

extern "C" void kernel_launch(void* const* d_in, const int* in_sizes, int n_in,
                              void* d_out, int out_size, void* d_ws, size_t ws_size,
                              hipStream_t stream) {
  const float* feat = (const float*)d_in[0];
  const float* adj  = (const float*)d_in[1];
  const float* aug  = (const float*)d_in[2];
  const float* W    = (const float*)d_in[3];
  const float* bias = (const float*)d_in[4];
  const float* pa   = (const float*)d_in[5];
  float* out = (float*)d_out;
  __bf16* Bp = (__bf16*)d_ws;                    // 4 MB packed seq_fts

  seq_fts_kernel<<<dim3(NROW / 64), 256, 0, stream>>>(feat, W, Bp);
  gcn_agg_kernel<<<dim3(NROW / 32, 2), 256, 0, stream>>>(
      adj, aug, Bp, bias, pa, out);
}

// Round 13
// 232.934 us; speedup vs baseline: 1.0523x; 1.0523x over previous
//
#include <hip/hip_runtime.h>

#define NROW 8192
#define INF  512
#define OUTF 256
#define M_ELEM (NROW * OUTF)   // 2,097,152 f32 per output matrix
#define NSTEP 32               // K-steps of 256

typedef __bf16 v8bf __attribute__((ext_vector_type(8)));
typedef __bf16 v4bf __attribute__((ext_vector_type(4)));
typedef float  v4f  __attribute__((ext_vector_type(4)));

__device__ __forceinline__ v8bf cvt_bf8(v4f u0, v4f u1) {
  v8bf v;
  v[0]=(__bf16)u0[0]; v[1]=(__bf16)u0[1]; v[2]=(__bf16)u0[2]; v[3]=(__bf16)u0[3];
  v[4]=(__bf16)u1[0]; v[5]=(__bf16)u1[1]; v[6]=(__bf16)u1[2]; v[7]=(__bf16)u1[3];
  return v;
}

// ---------------------------------------------------------------------------
// Kernel A: seq = feat @ W^T, bf16 MFMA, output in B-fragment-packed layout:
//   elem(m,o) -> (((m>>5)*16 + (o>>4))*64 + ((m>>3)&3)*16 + (o&15))*8 + (m&7)
// ---------------------------------------------------------------------------
__global__ __launch_bounds__(256) void seq_fts_kernel(
    const float* __restrict__ feat, const float* __restrict__ W,
    __bf16* __restrict__ Bp) {
  const int tid  = threadIdx.x;
  const int lane = tid & 63, w = tid >> 6;
  const int llo  = lane & 15, lhi = lane >> 4;
  const int row0 = blockIdx.x * 64;
  const int col0 = w * 64;

  v4f acc[4][4] = {};
#pragma unroll 1
  for (int kb = 0; kb < INF / 32; ++kb) {
    const int kofs = kb * 32 + lhi * 8;
    v8bf a[4], b[4];
#pragma unroll
    for (int i = 0; i < 4; ++i) {
      const float* p = feat + (size_t)(row0 + i * 16 + llo) * INF + kofs;
      a[i] = cvt_bf8(*(const v4f*)p, *(const v4f*)(p + 4));
    }
#pragma unroll
    for (int i = 0; i < 4; ++i) {
      const float* p = W + (size_t)(col0 + i * 16 + llo) * INF + kofs;
      b[i] = cvt_bf8(*(const v4f*)p, *(const v4f*)(p + 4));
    }
#pragma unroll
    for (int ri = 0; ri < 4; ++ri)
#pragma unroll
      for (int ci = 0; ci < 4; ++ci)
        acc[ri][ci] = __builtin_amdgcn_mfma_f32_16x16x32_bf16(
            a[ri], b[ci], acc[ri][ci], 0, 0, 0);
  }
#pragma unroll
  for (int ri = 0; ri < 4; ++ri)
#pragma unroll
    for (int ci = 0; ci < 4; ++ci) {
      const int mf = row0 + ri * 16 + lhi * 4;
      const int o  = col0 + ci * 16 + llo;
      size_t e = (((size_t)(mf >> 5) * 16 + (o >> 4)) * 64 +
                  ((mf >> 3) & 3) * 16 + (o & 15)) * 8 + (mf & 7);
      v4bf v;
      v[0] = (__bf16)acc[ri][ci][0]; v[1] = (__bf16)acc[ri][ci][1];
      v[2] = (__bf16)acc[ri][ci][2]; v[3] = (__bf16)acc[ri][ci][3];
      *(v4bf*)(Bp + e) = v;
    }
}

// ---------------------------------------------------------------------------
// Kernel B: out = prelu(adj @ seq + bias).
// REG-STAGED A: the adj stream goes global->VGPR (plain dwordx4, per-wave
// buffer-path MSHRs = m13's 6.3 TB/s regime) then ds_write_b128 into
// XOR-swizzled LDS. Hypothesis: global_load_lds' DMA path has a small
// per-CU outstanding window (~5 B/cy/CU HBM-cold, ~20 L2-hot per m97),
// which is what pinned R2..R12 at ~2.2-3 TB/s.
// Per step FIFO: bh0, bh1 (oldest), A(t+1) reg loads (newest) -> compute's
// B-waits never drain A; after compute vmcnt(0), swizzled ds_write, barrier.
// BM=64, BK=256 (1 KB/row extents), 8 waves, D=2 LDS (128 KB).
// ---------------------------------------------------------------------------
__global__ __launch_bounds__(512, 1) void gcn_agg_kernel(
    const float* __restrict__ adjA, const float* __restrict__ adjB,
    const __bf16* __restrict__ Bp, const float* __restrict__ bias,
    const float* __restrict__ prelu_a, float* __restrict__ out) {
  const int tid  = threadIdx.x;
  const int lane = tid & 63, w = tid >> 6;
  const int llo  = lane & 15, lhi = lane >> 4;
  const int wr   = w >> 2, wc = w & 3;     // 2 row-groups x 4 col-groups
  const int row0 = blockIdx.x * 64;
  const int z    = blockIdx.y;
  const float* __restrict__ adj = z ? adjB : adjA;

  __shared__ __align__(16) char LdsA[2][65536];   // 2 x (64 rows x 1 KB)

  v4f acc[2][4] = {};

  // --- A: 8 rows/wave, one 1 KB extent per row. Lane l loads floats
  // [l*4, l*4+4) of the row (linear, coalesced) into areg[i].
  v4f areg[8];
  auto issue_a = [&](int t) {
#pragma unroll
    for (int i = 0; i < 8; ++i) {
      const int r = w * 8 + i;
      const float* src =
          adj + (size_t)(row0 + r) * NROW + t * 256 + (lane << 2);
      areg[i] = *(const v4f*)src;
    }
  };
  // swizzled write: LDS row r slot (l ^ key(r)) <- lane l's 16 B.
  auto write_a = [&](int buf) {
#pragma unroll
    for (int i = 0; i < 8; ++i) {
      const int r   = w * 8 + i;
      const int key = ((r & 15) << 1) | ((r >> 3) & 1);
      *(v4f*)(&LdsA[buf][r * 1024 + ((lane ^ key) << 4)]) = areg[i];
    }
  };

  // --- B fragments, half-step granularity: [4 kk][4 ci] = 64 VGPR per half.
  const __bf16* __restrict__ Bpw = Bp + ((size_t)(wc * 4) * 64 + lane) * 8;
  auto load_bh = [&](int t, int h, v8bf (&b)[4][4]) {
#pragma unroll
    for (int kk = 0; kk < 4; ++kk)
#pragma unroll
      for (int ci = 0; ci < 4; ++ci)
        b[kk][ci] = *(const v8bf*)(
            Bpw + ((size_t)((t * 8 + h * 4 + kk) * 16 + ci)) * 512);
  };

  auto compute_h = [&](int buf, int h, v8bf (&b)[4][4]) {
    const char* ab = &LdsA[buf][0];
#pragma unroll
    for (int kk = 0; kk < 4; ++kk) {
      const int kg = h * 4 + kk;
      v8bf af[2];
#pragma unroll
      for (int rt = 0; rt < 2; ++rt) {
        const int r   = wr * 32 + rt * 16 + llo;
        const int key = ((r & 15) << 1) | ((r >> 3) & 1);
        const char* base = ab + r * 1024;
        v4f u0 = *(const v4f*)(base + (((kg * 8 + lhi * 2    ) ^ key) << 4));
        v4f u1 = *(const v4f*)(base + (((kg * 8 + lhi * 2 + 1) ^ key) << 4));
        af[rt] = cvt_bf8(u0, u1);
      }
#pragma unroll
      for (int ci = 0; ci < 4; ++ci)
#pragma unroll
        for (int rt = 0; rt < 2; ++rt)
          acc[rt][ci] = __builtin_amdgcn_mfma_f32_16x16x32_bf16(
              af[rt], b[kk][ci], acc[rt][ci], 0, 0, 0);
    }
  };

  // prologue: A(0) -> LDS[0]
  issue_a(0);
  asm volatile("s_waitcnt vmcnt(0)" ::: "memory");
  write_a(0);
  asm volatile("s_waitcnt lgkmcnt(0)" ::: "memory");
  __builtin_amdgcn_s_barrier();

  v8bf bh0[4][4], bh1[4][4];
#pragma unroll 1
  for (int t = 0; t < NSTEP; ++t) {
    load_bh(t, 0, bh0);                               // oldest in FIFO
    __builtin_amdgcn_sched_barrier(0);
    load_bh(t, 1, bh1);
    __builtin_amdgcn_sched_barrier(0);
    if (t + 1 < NSTEP) issue_a(t + 1);                // newest in FIFO
    __builtin_amdgcn_sched_barrier(0);
    compute_h(t & 1, 0, bh0);   // waits bh0 -> bh1 + A stay in flight
    compute_h(t & 1, 1, bh1);   // waits bh1 -> A stays in flight
    __builtin_amdgcn_sched_barrier(0);
    if (t + 1 < NSTEP) {
      asm volatile("s_waitcnt vmcnt(0)" ::: "memory");  // A(t+1) landed
      write_a((t + 1) & 1);
      asm volatile("s_waitcnt lgkmcnt(0)" ::: "memory");
    }
    __builtin_amdgcn_s_barrier();
  }

  // epilogue: bias + prelu, direct store
  const float slope = prelu_a[0];
  float* __restrict__ outp = out + (size_t)z * M_ELEM;
#pragma unroll
  for (int ci = 0; ci < 4; ++ci) {
    const int o  = wc * 64 + ci * 16 + llo;
    const float bs = bias[o];
#pragma unroll
    for (int rt = 0; rt < 2; ++rt) {
      const int m = row0 + wr * 32 + rt * 16 + lhi * 4;
#pragma unroll
      for (int r = 0; r < 4; ++r) {
        float v = acc[rt][ci][r] + bs;
        outp[(size_t)(m + r) * OUTF + o] = v >= 0.f ? v : slope * v;
      }
    }
  }
}

extern "C" void kernel_launch(void* const* d_in, const int* in_sizes, int n_in,
                              void* d_out, int out_size, void* d_ws, size_t ws_size,
                              hipStream_t stream) {
  const float* feat = (const float*)d_in[0];
  const float* adj  = (const float*)d_in[1];
  const float* aug  = (const float*)d_in[2];
  const float* W    = (const float*)d_in[3];
  const float* bias = (const float*)d_in[4];
  const float* pa   = (const float*)d_in[5];
  float* out = (float*)d_out;
  __bf16* Bp = (__bf16*)d_ws;                    // 4 MB packed seq_fts

  seq_fts_kernel<<<dim3(NROW / 64), 256, 0, stream>>>(feat, W, Bp);
  gcn_agg_kernel<<<dim3(NROW / 64, 2), 512, 0, stream>>>(
      adj, aug, Bp, bias, pa, out);
}

// Round 14
// 193.072 us; speedup vs baseline: 1.2696x; 1.2065x over previous
//
#include <hip/hip_runtime.h>

#define NROW 8192
#define INF  512
#define OUTF 256
#define M_ELEM (NROW * OUTF)   // 2,097,152 f32 per output matrix
#define NSTEP 32               // K-steps of 256

typedef __bf16 v8bf __attribute__((ext_vector_type(8)));
typedef __bf16 v4bf __attribute__((ext_vector_type(4)));
typedef float  v4f  __attribute__((ext_vector_type(4)));

__device__ __forceinline__ v8bf cvt_bf8(v4f u0, v4f u1) {
  v8bf v;
  v[0]=(__bf16)u0[0]; v[1]=(__bf16)u0[1]; v[2]=(__bf16)u0[2]; v[3]=(__bf16)u0[3];
  v[4]=(__bf16)u1[0]; v[5]=(__bf16)u1[1]; v[6]=(__bf16)u1[2]; v[7]=(__bf16)u1[3];
  return v;
}

// ---------------------------------------------------------------------------
// Kernel A: seq = feat @ W^T, bf16 MFMA, output in B-fragment-packed layout:
//   elem(m,o) -> (((m>>5)*16 + (o>>4))*64 + ((m>>3)&3)*16 + (o&15))*8 + (m&7)
// ---------------------------------------------------------------------------
__global__ __launch_bounds__(256) void seq_fts_kernel(
    const float* __restrict__ feat, const float* __restrict__ W,
    __bf16* __restrict__ Bp) {
  const int tid  = threadIdx.x;
  const int lane = tid & 63, w = tid >> 6;
  const int llo  = lane & 15, lhi = lane >> 4;
  const int row0 = blockIdx.x * 64;
  const int col0 = w * 64;

  v4f acc[4][4] = {};
#pragma unroll 1
  for (int kb = 0; kb < INF / 32; ++kb) {
    const int kofs = kb * 32 + lhi * 8;
    v8bf a[4], b[4];
#pragma unroll
    for (int i = 0; i < 4; ++i) {
      const float* p = feat + (size_t)(row0 + i * 16 + llo) * INF + kofs;
      a[i] = cvt_bf8(*(const v4f*)p, *(const v4f*)(p + 4));
    }
#pragma unroll
    for (int i = 0; i < 4; ++i) {
      const float* p = W + (size_t)(col0 + i * 16 + llo) * INF + kofs;
      b[i] = cvt_bf8(*(const v4f*)p, *(const v4f*)(p + 4));
    }
#pragma unroll
    for (int ri = 0; ri < 4; ++ri)
#pragma unroll
      for (int ci = 0; ci < 4; ++ci)
        acc[ri][ci] = __builtin_amdgcn_mfma_f32_16x16x32_bf16(
            a[ri], b[ci], acc[ri][ci], 0, 0, 0);
  }
#pragma unroll
  for (int ri = 0; ri < 4; ++ri)
#pragma unroll
    for (int ci = 0; ci < 4; ++ci) {
      const int mf = row0 + ri * 16 + lhi * 4;
      const int o  = col0 + ci * 16 + llo;
      size_t e = (((size_t)(mf >> 5) * 16 + (o >> 4)) * 64 +
                  ((mf >> 3) & 3) * 16 + (o & 15)) * 8 + (mf & 7);
      v4bf v;
      v[0] = (__bf16)acc[ri][ci][0]; v[1] = (__bf16)acc[ri][ci][1];
      v[2] = (__bf16)acc[ri][ci][2]; v[3] = (__bf16)acc[ri][ci][3];
      *(v4bf*)(Bp + e) = v;
    }
}

// ---------------------------------------------------------------------------
// Kernel B: out = prelu(adj @ seq + bias).
// R9 geometry (BM=64, 8 waves 2x4, BK=256, D=2 LDS), but A staged via
// REGISTERS (plain NT dwordx4: per-wave MSHR path = m13's 6.3 TB/s regime,
// escaping the global_load_lds DMA engine's ~5-7 B/cy/CU HBM-cold cap seen
// across R2..R12) then swizzled ds_write. Register pressure engineered low:
// B double-buffered at kk granularity (b[2][4] = 64 VGPR, not 128), A 32,
// acc 32 -> ~150 total, so the allocator can't collapse the A pipeline.
// FIFO per step: bk0, bk1, A(t+1), bk2..bk7 -> A drained at bk2-consume
// (~3.5k cy window > loaded latency); write needs it only at step end.
// ---------------------------------------------------------------------------
__global__ __launch_bounds__(512, 2)
__attribute__((amdgpu_waves_per_eu(2, 2)))
void gcn_agg_kernel(
    const float* __restrict__ adjA, const float* __restrict__ adjB,
    const __bf16* __restrict__ Bp, const float* __restrict__ bias,
    const float* __restrict__ prelu_a, float* __restrict__ out) {
  const int tid  = threadIdx.x;
  const int lane = tid & 63, w = tid >> 6;
  const int llo  = lane & 15, lhi = lane >> 4;
  const int wr   = w >> 2, wc = w & 3;     // 2 row-groups x 4 col-groups
  const int row0 = blockIdx.x * 64;
  const int z    = blockIdx.y;
  const float* __restrict__ adj = z ? adjB : adjA;

  __shared__ __align__(16) char LdsA[2][65536];   // 2 x (64 rows x 1 KB)

  v4f acc[2][4] = {};

  // --- A: 8 rows/wave, one 1 KB extent per row; lane l holds floats
  // [l*4, l*4+4) of the row (linear, coalesced, NT).
  v4f areg[8];
  auto issue_a = [&](int t) {
#pragma unroll
    for (int i = 0; i < 8; ++i) {
      const int r = w * 8 + i;
      const float* src =
          adj + (size_t)(row0 + r) * NROW + t * 256 + (lane << 2);
      areg[i] = __builtin_nontemporal_load((const v4f*)src);
    }
  };
  // swizzled write: LDS row r slot (l ^ key(r)) <- lane l's 16 B.
  auto write_a = [&](int buf) {
#pragma unroll
    for (int i = 0; i < 8; ++i) {
      const int r   = w * 8 + i;
      const int key = ((r & 15) << 1) | ((r >> 3) & 1);
      *(v4f*)(&LdsA[buf][r * 1024 + ((lane ^ key) << 4)]) = areg[i];
    }
  };

  // --- B fragments, kk-group granularity: [4 ci] = 32 VGPR per group.
  const __bf16* __restrict__ Bpw = Bp + ((size_t)(wc * 4) * 64 + lane) * 8;
  auto load_bg = [&](int t, int g, v8bf (&bb)[4]) {
#pragma unroll
    for (int ci = 0; ci < 4; ++ci)
      bb[ci] = *(const v8bf*)(
          Bpw + ((size_t)((t * 8 + g) * 16 + ci)) * 512);
  };

  auto compute_g = [&](int buf, int kg, v8bf (&bb)[4]) {
    const char* ab = &LdsA[buf][0];
    v8bf af[2];
#pragma unroll
    for (int rt = 0; rt < 2; ++rt) {
      const int r   = wr * 32 + rt * 16 + llo;
      const int key = ((r & 15) << 1) | ((r >> 3) & 1);
      const char* base = ab + r * 1024;
      v4f u0 = *(const v4f*)(base + (((kg * 8 + lhi * 2    ) ^ key) << 4));
      v4f u1 = *(const v4f*)(base + (((kg * 8 + lhi * 2 + 1) ^ key) << 4));
      af[rt] = cvt_bf8(u0, u1);
    }
#pragma unroll
    for (int ci = 0; ci < 4; ++ci)
#pragma unroll
      for (int rt = 0; rt < 2; ++rt)
        acc[rt][ci] = __builtin_amdgcn_mfma_f32_16x16x32_bf16(
            af[rt], bb[ci], acc[rt][ci], 0, 0, 0);
  };

  // prologue: A(0) -> LDS[0]
  issue_a(0);
  asm volatile("s_waitcnt vmcnt(0)" ::: "memory");
  write_a(0);
  asm volatile("s_waitcnt lgkmcnt(0)" ::: "memory");
  __builtin_amdgcn_s_barrier();

  v8bf b[2][4];
#pragma unroll 1
  for (int t = 0; t < NSTEP; ++t) {
    load_bg(t, 0, b[0]);                       // oldest
    __builtin_amdgcn_sched_barrier(0);
    load_bg(t, 1, b[1]);
    __builtin_amdgcn_sched_barrier(0);
    if (t + 1 < NSTEP) issue_a(t + 1);         // after bk0/bk1, before bk2
    __builtin_amdgcn_sched_barrier(0);
#pragma unroll
    for (int kg = 0; kg < 8; ++kg) {
      compute_g(t & 1, kg, b[kg & 1]);
      if (kg + 2 < 8) {
        __builtin_amdgcn_sched_barrier(0);
        load_bg(t, kg + 2, b[kg & 1]);
        __builtin_amdgcn_sched_barrier(0);
      }
    }
    __builtin_amdgcn_sched_barrier(0);
    if (t + 1 < NSTEP) {
      asm volatile("s_waitcnt vmcnt(0)" ::: "memory");  // A(t+1) landed
      write_a((t + 1) & 1);
      asm volatile("s_waitcnt lgkmcnt(0)" ::: "memory");
    }
    __builtin_amdgcn_s_barrier();
  }

  // epilogue: bias + prelu, direct store
  const float slope = prelu_a[0];
  float* __restrict__ outp = out + (size_t)z * M_ELEM;
#pragma unroll
  for (int ci = 0; ci < 4; ++ci) {
    const int o  = wc * 64 + ci * 16 + llo;
    const float bs = bias[o];
#pragma unroll
    for (int rt = 0; rt < 2; ++rt) {
      const int m = row0 + wr * 32 + rt * 16 + lhi * 4;
#pragma unroll
      for (int r = 0; r < 4; ++r) {
        float v = acc[rt][ci][r] + bs;
        outp[(size_t)(m + r) * OUTF + o] = v >= 0.f ? v : slope * v;
      }
    }
  }
}

extern "C" void kernel_launch(void* const* d_in, const int* in_sizes, int n_in,
                              void* d_out, int out_size, void* d_ws, size_t ws_size,
                              hipStream_t stream) {
  const float* feat = (const float*)d_in[0];
  const float* adj  = (const float*)d_in[1];
  const float* aug  = (const float*)d_in[2];
  const float* W    = (const float*)d_in[3];
  const float* bias = (const float*)d_in[4];
  const float* pa   = (const float*)d_in[5];
  float* out = (float*)d_out;
  __bf16* Bp = (__bf16*)d_ws;                    // 4 MB packed seq_fts

  seq_fts_kernel<<<dim3(NROW / 64), 256, 0, stream>>>(feat, W, Bp);
  gcn_agg_kernel<<<dim3(NROW / 64, 2), 512, 0, stream>>>(
      adj, aug, Bp, bias, pa, out);
}